// Round 10
// baseline (204.792 us; speedup 1.0000x reference)
//
#include <hip/hip_runtime.h>
#include <hip/hip_bf16.h>

typedef __attribute__((ext_vector_type(8))) short bf16x8;
typedef __attribute__((ext_vector_type(16))) float f32x16;
typedef __attribute__((ext_vector_type(4))) unsigned short ushort4v;

static __device__ __forceinline__ unsigned short f2bf(float f) {
  unsigned u = __float_as_uint(f);
  return (unsigned short)((u + 0x7FFFu + ((u >> 16) & 1u)) >> 16);
}
static __device__ __forceinline__ float silu_f(float v) { return v / (1.f + __expf(-v)); }

#define MFMA32(a, b, c) __builtin_amdgcn_mfma_f32_32x32x16_bf16((a), (b), (c), 0, 0, 0)

// ---- K0: fused weight pack (A-fragment order) + 4x4 avg pool ----
// A-frag pack: lane l holds row rb*32+(l&31), k = ks*16 + (l>>5)*8 + i.
// packed[((rb*NKS+ks)*64 + l)*8 + i]
__global__ void prep_k(const float* __restrict__ shw, const float* __restrict__ ew1,
                       const float* __restrict__ ew2, const float* __restrict__ x,
                       unsigned short* __restrict__ wshp, unsigned short* __restrict__ w1p,
                       unsigned short* __restrict__ w2p, float* __restrict__ xp) {
  const int bid = blockIdx.x;
  if (bid < 4352) {
    int idx = bid * 256 + threadIdx.x;
    if (idx < 65536) {  // shared_w [256,256], NKS=16
      int j = idx;
      int i = j & 7, l = (j >> 3) & 63, ks = (j >> 9) & 15, rb = j >> 13;
      int row = rb * 32 + (l & 31), k = ks * 16 + (l >> 5) * 8 + i;
      wshp[j] = f2bf(shw[row * 256 + k]);
    } else if (idx < 589824) {  // expert_w1 [4,512,256], NKS=16
      int j = idx - 65536;
      int i = j & 7, l = (j >> 3) & 63, ks = (j >> 9) & 15, rb = (j >> 13) & 15, e = j >> 17;
      int row = rb * 32 + (l & 31), k = ks * 16 + (l >> 5) * 8 + i;
      w1p[j] = f2bf(ew1[((size_t)e * 512 + row) * 256 + k]);
    } else if (idx < 1114112) {  // expert_w2 [4,256,512], NKS=32
      int j = idx - 589824;
      int i = j & 7, l = (j >> 3) & 63, ks = (j >> 9) & 31, rb = (j >> 14) & 7, e = j >> 17;
      int row = rb * 32 + (l & 31), k = ks * 16 + (l >> 5) * 8 + i;
      w2p[j] = f2bf(ew2[((size_t)e * 256 + row) * 512 + k]);
    }
  } else {
    int idx = (bid - 4352) * 256 + threadIdx.x;
    if (idx >= 16 * 256 * 196) return;
    int pj = idx % 14, tmp = idx / 14, pi = tmp % 14, bc = tmp / 14;
    const float* src = x + (size_t)bc * 3136 + pi * 4 * 56 + pj * 4;
    float s = 0.f;
#pragma unroll
    for (int u = 0; u < 4; ++u) {
      float4 v = *reinterpret_cast<const float4*>(src + u * 56);
      s += v.x + v.y + v.z + v.w;
    }
    xp[idx] = s * 0.0625f;
  }
}

// ---- K2: router 3x3 conv + SiLU + spatial sum. block=(b,r), 512 blocks. ----
// Double-buffered 16-channel chunks: stage(cc+1) issued before compute(cc),
// one barrier per chunk -> staging latency hides under compute.
__global__ __launch_bounds__(256) void router_conv_k(const float* __restrict__ xp,
                                                     const float* __restrict__ rw1,
                                                     float* __restrict__ hsum) {
  const int b = blockIdx.x >> 5, r = blockIdx.x & 31;
  __shared__ float wl[2304];
  __shared__ float xl[2][16][256];  // 2 x 16 channels, padded 16x16 planes
  __shared__ float red[4][196];
  __shared__ float red2[4];
  const int t = threadIdx.x;
  const int w = t >> 6, l = t & 63;
  for (int i = t; i < 2304; i += 256) wl[i] = rw1[r * 2304 + i];
  for (int i = t; i < 2 * 16 * 256; i += 256) (&xl[0][0][0])[i] = 0.f;  // borders stay 0
  const int ui = (l < 49) ? (l / 7) : 0, uj = (l < 49) ? (l % 7) : 0;
  float acc[4] = {0.f, 0.f, 0.f, 0.f};
  // stage chunk 0
  for (int i = t; i < 16 * 196; i += 256) {
    int c = i / 196, px = i % 196;
    xl[0][c][(px / 14 + 1) * 16 + (px % 14 + 1)] = xp[((size_t)b * 256 + c) * 196 + px];
  }
  __syncthreads();
  for (int cc = 0; cc < 16; ++cc) {
    if (cc < 15) {  // prefetch next chunk into other buffer
      for (int i = t; i < 16 * 196; i += 256) {
        int c = i / 196, px = i % 196;
        xl[(cc + 1) & 1][c][(px / 14 + 1) * 16 + (px % 14 + 1)] =
            xp[((size_t)b * 256 + (cc + 1) * 16 + c) * 196 + px];
      }
    }
    if (l < 49) {
      const float(*xb_buf)[256] = xl[cc & 1];
#pragma unroll
      for (int ci = 0; ci < 4; ++ci) {
        const int c = w * 4 + ci;
        float xv[4][4];
        const float* xb = &xb_buf[c][ui * 32 + uj * 2];
#pragma unroll
        for (int dr = 0; dr < 4; ++dr)
#pragma unroll
          for (int dc = 0; dc < 4; ++dc) xv[dr][dc] = xb[dr * 16 + dc];
        const float* wp = &wl[(cc * 16 + c) * 9];
        float wv[9];
#pragma unroll
        for (int j = 0; j < 9; ++j) wv[j] = wp[j];  // uniform addr -> broadcast
#pragma unroll
        for (int di = 0; di < 2; ++di)
#pragma unroll
          for (int dj = 0; dj < 2; ++dj) {
            float a = acc[di * 2 + dj];
#pragma unroll
            for (int du = 0; du < 3; ++du)
#pragma unroll
              for (int dv = 0; dv < 3; ++dv)
                a += xv[di + du][dj + dv] * wv[du * 3 + dv];
            acc[di * 2 + dj] = a;
          }
      }
    }
    __syncthreads();
  }
  if (l < 49) {
#pragma unroll
    for (int k = 0; k < 4; ++k) red[w][(ui * 7 + uj) * 4 + k] = acc[k];
  }
  __syncthreads();
  float s = 0.f;
  if (t < 196) {
    float tot = red[0][t] + red[1][t] + red[2][t] + red[3][t];
    s = silu_f(tot);
  }
#pragma unroll
  for (int off = 32; off > 0; off >>= 1) s += __shfl_down(s, off);
  if ((t & 63) == 0) red2[t >> 6] = s;
  __syncthreads();
  if (t == 0) hsum[b * 32 + r] = red2[0] + red2[1] + red2[2] + red2[3];
}

// ---- K3: logits -> softmax -> top-2 -> normalized weights ----
__global__ void topk_k(const float* __restrict__ hsum, const float* __restrict__ rw2,
                       float* __restrict__ selv, int* __restrict__ sele) {
  const int t = threadIdx.x;
  const int b = t >> 2, e = t & 3;
  float l = 0.f;
#pragma unroll
  for (int r = 0; r < 32; ++r) l += rw2[e * 32 + r] * hsum[b * 32 + r];
  l *= (1.f / 196.f);
  float m = fmaxf(l, __shfl_xor(l, 1));
  m = fmaxf(m, __shfl_xor(m, 2));
  float p = __expf(l - m);
  float sm = p + __shfl_xor(p, 1);
  sm += __shfl_xor(sm, 2);
  float prob = p / sm;
  float p0 = __shfl(prob, (b << 2) | 0);
  float p1 = __shfl(prob, (b << 2) | 1);
  float p2 = __shfl(prob, (b << 2) | 2);
  float p3 = __shfl(prob, (b << 2) | 3);
  if (e == 0) {
    float pr[4] = {p0, p1, p2, p3};
    int i1 = 0;
    for (int i = 1; i < 4; ++i)
      if (pr[i] > pr[i1]) i1 = i;
    int i2 = (i1 == 0) ? 1 : 0;
    for (int i = 0; i < 4; ++i) {
      if (i == i1 || i == i2) continue;
      if (pr[i] > pr[i2]) i2 = i;
    }
    float denom = pr[i1] + pr[i2] + 1e-6f;
    selv[b * 2 + 0] = pr[i1] / denom;
    selv[b * 2 + 1] = pr[i2] / denom;
    sele[b * 2 + 0] = i1;
    sele[b * 2 + 1] = i2;
  }
}

// ---- K4: producer/consumer MoE main. 8 waves x 64px, 64 KB LDS, VGPR<=128
// -> 2 blocks/CU x 8 waves = 4 waves/SIMD (2x prior occupancy).
// Producers (w 0-3): stage1 of 128-row hidden phase p+1 (rf1 cf2, hacc=32 reg),
//   v*silu -> hs[(p+1)&1]. Consumers (w 4-7): shared expert then stage2(p)
//   from hs[p&1] (rf2 cf2, oacc=64 reg). One barrier per phase; producer runs
//   exactly one phase ahead via double-buffered hs.
// xs: [kg 0..31][px 0..63][8] (32 KB). hs: [2][16][64][8] (2 x 16 KB).
__global__ __launch_bounds__(512, 4) void moe_main_k(
    const float* __restrict__ x, const unsigned short* __restrict__ wshp,
    const unsigned short* __restrict__ w1p, const unsigned short* __restrict__ w2p,
    const float* __restrict__ selv, const int* __restrict__ sele,
    float* __restrict__ out) {
  constexpr int HW = 3136;
  __shared__ __align__(16) unsigned short xs[32 * 64 * 8];     // 32 KB
  __shared__ __align__(16) unsigned short hs[2][16 * 64 * 8];  // 32 KB

  const int b = blockIdx.x / 49, tile = blockIdx.x - b * 49;
  const int px0 = tile * 64;
  const int t = threadIdx.x;
  const int w = t >> 6, l = t & 63;
  const int l31 = l & 31, lh = l >> 5;

  // ---- stage x tile: wave w stages channels w*32 .. +32, thread px = l ----
  {
    const float* xb = x + (size_t)b * 256 * HW + px0 + l;
#pragma unroll
    for (int cg = 0; cg < 4; ++cg) {
      const int c0 = w * 32 + cg * 8;
      alignas(16) unsigned short tmp[8];
#pragma unroll
      for (int i = 0; i < 8; ++i) tmp[i] = f2bf(xb[(size_t)(c0 + i) * HW]);
      *reinterpret_cast<bf16x8*>(&xs[((c0 >> 3) * 64 + l) * 8]) =
          *reinterpret_cast<const bf16x8*>(tmp);
    }
  }

  const int e0 = sele[b * 2 + 0], e1 = sele[b * 2 + 1];
  const float v0 = selv[b * 2 + 0], v1 = selv[b * 2 + 1];

  const unsigned short* xB0 = xs + (lh * 64 + l31) * 8;
  const unsigned short* xB1 = xB0 + 256;

  __syncthreads();  // B1: xs ready

  if (w < 4) {
    // ================= PRODUCER (waves 0-3) =================
    f32x16 hacc[2];
    // ---- phase 0 ----
    {
      const unsigned short* A1 = w1p + (size_t)((e0 * 16 + w) * 16) * 512 + l * 8;
#pragma unroll
      for (int j = 0; j < 2; ++j)
#pragma unroll
        for (int r = 0; r < 16; ++r) hacc[j][r] = 0.f;
      bf16x8 aC = *reinterpret_cast<const bf16x8*>(A1);
      bf16x8 b0C = *reinterpret_cast<const bf16x8*>(xB0);
      bf16x8 b1C = *reinterpret_cast<const bf16x8*>(xB1);
#pragma unroll
      for (int kk = 0; kk < 16; ++kk) {
        bf16x8 aN, b0N, b1N;
        if (kk < 15) {
          aN = *reinterpret_cast<const bf16x8*>(A1 + (kk + 1) * 512);
          b0N = *reinterpret_cast<const bf16x8*>(xB0 + (kk + 1) * 1024);
          b1N = *reinterpret_cast<const bf16x8*>(xB1 + (kk + 1) * 1024);
        }
        __builtin_amdgcn_s_setprio(1);
        hacc[0] = MFMA32(aC, b0C, hacc[0]);
        hacc[1] = MFMA32(aC, b1C, hacc[1]);
        __builtin_amdgcn_s_setprio(0);
        aC = aN; b0C = b0N; b1C = b1N;
      }
#pragma unroll
      for (int cf = 0; cf < 2; ++cf)
#pragma unroll
        for (int g = 0; g < 4; ++g) {
          alignas(8) unsigned short pk[4];
#pragma unroll
          for (int j = 0; j < 4; ++j) pk[j] = f2bf(v0 * silu_f(hacc[cf][g * 4 + j]));
          const int ui2 = ((w * 4 + g) * 64 + cf * 32 + l31) * 8 + lh * 4;
          *reinterpret_cast<ushort4v*>(&hs[0][ui2]) = *reinterpret_cast<const ushort4v*>(pk);
        }
    }
    __syncthreads();  // B2: hs[0] ready
#pragma unroll 1
    for (int q = 0; q < 8; ++q) {
      if (q < 7) {
        const int p = q + 1;
        const int e = (p >> 2) ? e1 : e0, ch = p & 3;
        const float v = (p >> 2) ? v1 : v0;
        const unsigned short* A1 =
            w1p + (size_t)((e * 16 + ch * 4 + w) * 16) * 512 + l * 8;
#pragma unroll
        for (int j = 0; j < 2; ++j)
#pragma unroll
          for (int r = 0; r < 16; ++r) hacc[j][r] = 0.f;
        bf16x8 aC = *reinterpret_cast<const bf16x8*>(A1);
        bf16x8 b0C = *reinterpret_cast<const bf16x8*>(xB0);
        bf16x8 b1C = *reinterpret_cast<const bf16x8*>(xB1);
#pragma unroll
        for (int kk = 0; kk < 16; ++kk) {
          bf16x8 aN, b0N, b1N;
          if (kk < 15) {
            aN = *reinterpret_cast<const bf16x8*>(A1 + (kk + 1) * 512);
            b0N = *reinterpret_cast<const bf16x8*>(xB0 + (kk + 1) * 1024);
            b1N = *reinterpret_cast<const bf16x8*>(xB1 + (kk + 1) * 1024);
          }
          __builtin_amdgcn_s_setprio(1);
          hacc[0] = MFMA32(aC, b0C, hacc[0]);
          hacc[1] = MFMA32(aC, b1C, hacc[1]);
          __builtin_amdgcn_s_setprio(0);
          aC = aN; b0C = b0N; b1C = b1N;
        }
        // write hs[p&1]; safe: its last readers (stage2(p-2)) were ordered by
        // the barrier at end of phase p-2.
#pragma unroll
        for (int cf = 0; cf < 2; ++cf)
#pragma unroll
          for (int g = 0; g < 4; ++g) {
            alignas(8) unsigned short pk[4];
#pragma unroll
            for (int j = 0; j < 4; ++j) pk[j] = f2bf(v * silu_f(hacc[cf][g * 4 + j]));
            const int ui2 = ((w * 4 + g) * 64 + cf * 32 + l31) * 8 + lh * 4;
            *reinterpret_cast<ushort4v*>(&hs[p & 1][ui2]) =
                *reinterpret_cast<const ushort4v*>(pk);
          }
      }
      __syncthreads();  // end of phase q
    }
  } else {
    // ================= CONSUMER (waves 4-7) =================
    const int wc = w - 4;  // out rows wc*64 .. +64
    f32x16 oacc[2][2];
#pragma unroll
    for (int i = 0; i < 2; ++i)
#pragma unroll
      for (int j = 0; j < 2; ++j)
#pragma unroll
        for (int r = 0; r < 16; ++r) oacc[i][j][r] = 0.f;

    // ---- shared expert: rf2 cf2, K=256 ----
    {
      const unsigned short* As = wshp + (size_t)(wc * 2) * 16 * 512 + l * 8;
      bf16x8 a0C = *reinterpret_cast<const bf16x8*>(As);
      bf16x8 a1C = *reinterpret_cast<const bf16x8*>(As + 8192);
      bf16x8 b0C = *reinterpret_cast<const bf16x8*>(xB0);
      bf16x8 b1C = *reinterpret_cast<const bf16x8*>(xB1);
#pragma unroll
      for (int kk = 0; kk < 16; ++kk) {
        bf16x8 a0N, a1N, b0N, b1N;
        if (kk < 15) {
          a0N = *reinterpret_cast<const bf16x8*>(As + (kk + 1) * 512);
          a1N = *reinterpret_cast<const bf16x8*>(As + 8192 + (kk + 1) * 512);
          b0N = *reinterpret_cast<const bf16x8*>(xB0 + (kk + 1) * 1024);
          b1N = *reinterpret_cast<const bf16x8*>(xB1 + (kk + 1) * 1024);
        }
        __builtin_amdgcn_s_setprio(1);
        oacc[0][0] = MFMA32(a0C, b0C, oacc[0][0]);
        oacc[0][1] = MFMA32(a0C, b1C, oacc[0][1]);
        oacc[1][0] = MFMA32(a1C, b0C, oacc[1][0]);
        oacc[1][1] = MFMA32(a1C, b1C, oacc[1][1]);
        __builtin_amdgcn_s_setprio(0);
        a0C = a0N; a1C = a1N; b0C = b0N; b1C = b1N;
      }
    }
#pragma unroll
    for (int i = 0; i < 2; ++i)
#pragma unroll
      for (int j = 0; j < 2; ++j)
#pragma unroll
        for (int r = 0; r < 16; ++r) oacc[i][j][r] = silu_f(oacc[i][j][r]);

    __syncthreads();  // B2: hs[0] ready
#pragma unroll 1
    for (int q = 0; q < 8; ++q) {
      const int e = (q >> 2) ? e1 : e0, ch = q & 3;
      const unsigned short* A2 =
          w2p + ((size_t)(e * 8 + wc * 2) * 32 + ch * 8) * 512 + l * 8;
      const unsigned short* hB0 = hs[q & 1] + (lh * 64 + l31) * 8;
      const unsigned short* hB1 = hB0 + 256;
      bf16x8 a0C = *reinterpret_cast<const bf16x8*>(A2);
      bf16x8 a1C = *reinterpret_cast<const bf16x8*>(A2 + 16384);
      bf16x8 h0C = *reinterpret_cast<const bf16x8*>(hB0);
      bf16x8 h1C = *reinterpret_cast<const bf16x8*>(hB1);
#pragma unroll
      for (int kk = 0; kk < 8; ++kk) {
        bf16x8 a0N, a1N, h0N, h1N;
        if (kk < 7) {
          a0N = *reinterpret_cast<const bf16x8*>(A2 + (kk + 1) * 512);
          a1N = *reinterpret_cast<const bf16x8*>(A2 + 16384 + (kk + 1) * 512);
          h0N = *reinterpret_cast<const bf16x8*>(hB0 + (kk + 1) * 1024);
          h1N = *reinterpret_cast<const bf16x8*>(hB1 + (kk + 1) * 1024);
        }
        __builtin_amdgcn_s_setprio(1);
        oacc[0][0] = MFMA32(a0C, h0C, oacc[0][0]);
        oacc[0][1] = MFMA32(a0C, h1C, oacc[0][1]);
        oacc[1][0] = MFMA32(a1C, h0C, oacc[1][0]);
        oacc[1][1] = MFMA32(a1C, h1C, oacc[1][1]);
        __builtin_amdgcn_s_setprio(0);
        a0C = a0N; a1C = a1N; h0C = h0N; h1C = h1N;
      }
      __syncthreads();  // end of phase q
    }

    // ---- write out[b, o, px] ----
#pragma unroll
    for (int rfi = 0; rfi < 2; ++rfi)
#pragma unroll
      for (int cf = 0; cf < 2; ++cf)
#pragma unroll
        for (int r = 0; r < 16; ++r) {
          const int o = wc * 64 + rfi * 32 + (r & 3) + 8 * (r >> 2) + 4 * lh;
          out[((size_t)b * 256 + o) * HW + px0 + cf * 32 + l31] = oacc[rfi][cf][r];
        }
  }
}

extern "C" void kernel_launch(void* const* d_in, const int* in_sizes, int n_in,
                              void* d_out, int out_size, void* d_ws, size_t ws_size,
                              hipStream_t stream) {
  const float* x = (const float*)d_in[0];
  const float* rw1 = (const float*)d_in[1];
  const float* rw2 = (const float*)d_in[2];
  const float* ew1 = (const float*)d_in[3];
  const float* ew2 = (const float*)d_in[4];
  const float* shw = (const float*)d_in[5];
  float* out = (float*)d_out;
  char* ws = (char*)d_ws;

  float* xp = (float*)(ws);                                // 3,211,264 B
  float* hsum = (float*)(ws + 3211264);
  float* selv = (float*)(ws + 3213312);
  int* sele = (int*)(ws + 3213440);
  unsigned short* wshp = (unsigned short*)(ws + 3213568);  // 128 KB
  unsigned short* w1p = wshp + 65536;                      // 1 MB
  unsigned short* w2p = w1p + 524288;                      // 1 MB

  prep_k<<<7488, 256, 0, stream>>>(shw, ew1, ew2, x, wshp, w1p, w2p, xp);
  router_conv_k<<<512, 256, 0, stream>>>(xp, rw1, hsum);
  topk_k<<<1, 64, 0, stream>>>(hsum, rw2, selv, sele);
  moe_main_k<<<784, 512, 0, stream>>>(x, wshp, w1p, w2p, selv, sele, out);
}

// Round 11
// 169.431 us; speedup vs baseline: 1.2087x; 1.2087x over previous
//
#include <hip/hip_runtime.h>
#include <hip/hip_bf16.h>

typedef __attribute__((ext_vector_type(8))) short bf16x8;
typedef __attribute__((ext_vector_type(16))) float f32x16;
typedef __attribute__((ext_vector_type(4))) unsigned short ushort4v;

static __device__ __forceinline__ unsigned short f2bf(float f) {
  unsigned u = __float_as_uint(f);
  return (unsigned short)((u + 0x7FFFu + ((u >> 16) & 1u)) >> 16);
}
static __device__ __forceinline__ float silu_f(float v) { return v / (1.f + __expf(-v)); }

#define MFMA32(a, b, c) __builtin_amdgcn_mfma_f32_32x32x16_bf16((a), (b), (c), 0, 0, 0)
#define SBAR() __builtin_amdgcn_sched_barrier(0x102)  // only VALU/DS_READ may cross

// ---- K0: fused weight pack (A-fragment order) + 4x4 avg pool ----
// A-frag pack: lane l holds row rb*32+(l&31), k = ks*16 + (l>>5)*8 + i.
// packed[((rb*NKS+ks)*64 + l)*8 + i]
__global__ void prep_k(const float* __restrict__ shw, const float* __restrict__ ew1,
                       const float* __restrict__ ew2, const float* __restrict__ x,
                       unsigned short* __restrict__ wshp, unsigned short* __restrict__ w1p,
                       unsigned short* __restrict__ w2p, float* __restrict__ xp) {
  const int bid = blockIdx.x;
  if (bid < 4352) {
    int idx = bid * 256 + threadIdx.x;
    if (idx < 65536) {  // shared_w [256,256], NKS=16
      int j = idx;
      int i = j & 7, l = (j >> 3) & 63, ks = (j >> 9) & 15, rb = j >> 13;
      int row = rb * 32 + (l & 31), k = ks * 16 + (l >> 5) * 8 + i;
      wshp[j] = f2bf(shw[row * 256 + k]);
    } else if (idx < 589824) {  // expert_w1 [4,512,256], NKS=16
      int j = idx - 65536;
      int i = j & 7, l = (j >> 3) & 63, ks = (j >> 9) & 15, rb = (j >> 13) & 15, e = j >> 17;
      int row = rb * 32 + (l & 31), k = ks * 16 + (l >> 5) * 8 + i;
      w1p[j] = f2bf(ew1[((size_t)e * 512 + row) * 256 + k]);
    } else if (idx < 1114112) {  // expert_w2 [4,256,512], NKS=32
      int j = idx - 589824;
      int i = j & 7, l = (j >> 3) & 63, ks = (j >> 9) & 31, rb = (j >> 14) & 7, e = j >> 17;
      int row = rb * 32 + (l & 31), k = ks * 16 + (l >> 5) * 8 + i;
      w2p[j] = f2bf(ew2[((size_t)e * 256 + row) * 512 + k]);
    }
  } else {
    int idx = (bid - 4352) * 256 + threadIdx.x;
    if (idx >= 16 * 256 * 196) return;
    int pj = idx % 14, tmp = idx / 14, pi = tmp % 14, bc = tmp / 14;
    const float* src = x + (size_t)bc * 3136 + pi * 4 * 56 + pj * 4;
    float s = 0.f;
#pragma unroll
    for (int u = 0; u < 4; ++u) {
      float4 v = *reinterpret_cast<const float4*>(src + u * 56);
      s += v.x + v.y + v.z + v.w;
    }
    xp[idx] = s * 0.0625f;
  }
}

// ---- K2: router 3x3 conv (pad 1) + SiLU + spatial sum -> hsum[16,32] ----
// (reverted to the proven R2/R4 version)
__global__ __launch_bounds__(256) void router_conv_k(const float* __restrict__ xp,
                                                     const float* __restrict__ rw1,
                                                     float* __restrict__ hsum) {
  const int b = blockIdx.x >> 5, r = blockIdx.x & 31;
  __shared__ float wl[2304];
  __shared__ float xl[32][256];
  __shared__ float red[4];
  const int t = threadIdx.x;
  for (int i = t; i < 2304; i += 256) wl[i] = rw1[r * 2304 + i];
  for (int i = t; i < 32 * 256; i += 256) (&xl[0][0])[i] = 0.f;
  const int pi = t / 14, pj = t % 14;
  float acc = 0.f;
  for (int cc = 0; cc < 8; ++cc) {
    __syncthreads();
    for (int i = t; i < 32 * 196; i += 256) {
      int c = i / 196, px = i % 196;
      xl[c][(px / 14 + 1) * 16 + (px % 14 + 1)] =
          xp[((size_t)b * 256 + cc * 32 + c) * 196 + px];
    }
    __syncthreads();
    if (t < 196) {
      for (int c = 0; c < 32; ++c) {
        const float* wp = &wl[(cc * 32 + c) * 9];
        const float* xc = &xl[c][pi * 16 + pj];
#pragma unroll
        for (int u = 0; u < 3; ++u)
#pragma unroll
          for (int v = 0; v < 3; ++v) acc += xc[u * 16 + v] * wp[u * 3 + v];
      }
    }
  }
  float s = (t < 196) ? silu_f(acc) : 0.f;
#pragma unroll
  for (int off = 32; off > 0; off >>= 1) s += __shfl_down(s, off);
  if ((t & 63) == 0) red[t >> 6] = s;
  __syncthreads();
  if (t == 0) hsum[b * 32 + r] = red[0] + red[1] + red[2] + red[3];
}

// ---- K3: logits -> softmax -> top-2 -> normalized weights ----
__global__ void topk_k(const float* __restrict__ hsum, const float* __restrict__ rw2,
                       float* __restrict__ selv, int* __restrict__ sele) {
  const int t = threadIdx.x;
  const int b = t >> 2, e = t & 3;
  float l = 0.f;
#pragma unroll
  for (int r = 0; r < 32; ++r) l += rw2[e * 32 + r] * hsum[b * 32 + r];
  l *= (1.f / 196.f);
  float m = fmaxf(l, __shfl_xor(l, 1));
  m = fmaxf(m, __shfl_xor(m, 2));
  float p = __expf(l - m);
  float sm = p + __shfl_xor(p, 1);
  sm += __shfl_xor(sm, 2);
  float prob = p / sm;
  float p0 = __shfl(prob, (b << 2) | 0);
  float p1 = __shfl(prob, (b << 2) | 1);
  float p2 = __shfl(prob, (b << 2) | 2);
  float p3 = __shfl(prob, (b << 2) | 3);
  if (e == 0) {
    float pr[4] = {p0, p1, p2, p3};
    int i1 = 0;
    for (int i = 1; i < 4; ++i)
      if (pr[i] > pr[i1]) i1 = i;
    int i2 = (i1 == 0) ? 1 : 0;
    for (int i = 0; i < 4; ++i) {
      if (i == i1 || i == i2) continue;
      if (pr[i] > pr[i2]) i2 = i;
    }
    float denom = pr[i1] + pr[i2] + 1e-6f;
    selv[b * 2 + 0] = pr[i1] / denom;
    selv[b * 2 + 1] = pr[i2] / denom;
    sele[b * 2 + 0] = i1;
    sele[b * 2 + 1] = i2;
  }
}

// ---- K4: producer/consumer MoE main with burst A-preload.
// 8 waves x 64px, 64 KB LDS, VGPR<=128 -> 2 blocks/CU = 4 waves/SIMD.
// Producers (w 0-3): stage1 of 128-row hidden phase p+1: burst-load all 16
//   A-frags (64 VGPR) -> MFMA cluster; v*silu -> hs[(p+1)&1].
// Consumers (w 4-7): shared expert then stage2(p) from hs[p&1]: 2 groups of
//   {burst 8 A-frags -> 16 MFMAs}. One barrier per phase.
// xs: [kg 0..31][px 0..63][8] (32 KB). hs: [2][16][64][8] (2 x 16 KB).
__global__ __launch_bounds__(512, 4) void moe_main_k(
    const float* __restrict__ x, const unsigned short* __restrict__ wshp,
    const unsigned short* __restrict__ w1p, const unsigned short* __restrict__ w2p,
    const float* __restrict__ selv, const int* __restrict__ sele,
    float* __restrict__ out) {
  constexpr int HW = 3136;
  __shared__ __align__(16) unsigned short xs[32 * 64 * 8];     // 32 KB
  __shared__ __align__(16) unsigned short hs[2][16 * 64 * 8];  // 32 KB

  const int b = blockIdx.x / 49, tile = blockIdx.x - b * 49;
  const int px0 = tile * 64;
  const int t = threadIdx.x;
  const int w = t >> 6, l = t & 63;
  const int l31 = l & 31, lh = l >> 5;

  // ---- stage x tile: wave w stages channels w*32 .. +32, thread px = l ----
  {
    const float* xb = x + (size_t)b * 256 * HW + px0 + l;
#pragma unroll
    for (int cg = 0; cg < 4; ++cg) {
      const int c0 = w * 32 + cg * 8;
      alignas(16) unsigned short tmp[8];
#pragma unroll
      for (int i = 0; i < 8; ++i) tmp[i] = f2bf(xb[(size_t)(c0 + i) * HW]);
      *reinterpret_cast<bf16x8*>(&xs[((c0 >> 3) * 64 + l) * 8]) =
          *reinterpret_cast<const bf16x8*>(tmp);
    }
  }

  const int e0 = sele[b * 2 + 0], e1 = sele[b * 2 + 1];
  const float v0 = selv[b * 2 + 0], v1 = selv[b * 2 + 1];

  const unsigned short* xB0 = xs + (lh * 64 + l31) * 8;
  const unsigned short* xB1 = xB0 + 256;

  __syncthreads();  // B1: xs ready

  if (w < 4) {
    // ================= PRODUCER (waves 0-3) =================
    f32x16 hacc[2];
#pragma unroll 1
    for (int q = 0; q < 8; ++q) {
      // compute phase p = q for q==0 pre-loop style: phase index = q (phase 0
      // before first barrier handled as q==0 here; consumer is doing shared
      // expert during our phase 0)
      const int p = q;
      const int e = (p >> 2) ? e1 : e0, ch = p & 3;
      const float v = (p >> 2) ? v1 : v0;
      const unsigned short* A1 =
          w1p + (size_t)((e * 16 + ch * 4 + w) * 16) * 512 + l * 8;
#pragma unroll
      for (int j = 0; j < 2; ++j)
#pragma unroll
        for (int r = 0; r < 16; ++r) hacc[j][r] = 0.f;
      // burst-load all 16 A-frags (64 VGPR) -> full MLP, one latency
      bf16x8 af[16];
#pragma unroll
      for (int j = 0; j < 16; ++j)
        af[j] = *reinterpret_cast<const bf16x8*>(A1 + j * 512);
      SBAR();
      __builtin_amdgcn_s_setprio(1);
#pragma unroll
      for (int j = 0; j < 16; ++j) {
        const bf16x8 b0 = *reinterpret_cast<const bf16x8*>(xB0 + j * 1024);
        const bf16x8 b1 = *reinterpret_cast<const bf16x8*>(xB1 + j * 1024);
        hacc[0] = MFMA32(af[j], b0, hacc[0]);
        hacc[1] = MFMA32(af[j], b1, hacc[1]);
      }
      __builtin_amdgcn_s_setprio(0);
      // v*silu -> packed bf16 (VALU only, before barrier)
      ushort4v pk[2][4];
#pragma unroll
      for (int cf = 0; cf < 2; ++cf)
#pragma unroll
        for (int g = 0; g < 4; ++g) {
          alignas(8) unsigned short tmp[4];
#pragma unroll
          for (int j = 0; j < 4; ++j) tmp[j] = f2bf(v * silu_f(hacc[cf][g * 4 + j]));
          pk[cf][g] = *reinterpret_cast<const ushort4v*>(tmp);
        }
      // write hs[p&1]; safe: last readers (stage2(p-2)) were barrier-ordered.
#pragma unroll
      for (int cf = 0; cf < 2; ++cf)
#pragma unroll
        for (int g = 0; g < 4; ++g) {
          const int ui2 = ((w * 4 + g) * 64 + cf * 32 + l31) * 8 + lh * 4;
          *reinterpret_cast<ushort4v*>(&hs[p & 1][ui2]) = pk[cf][g];
        }
      __syncthreads();  // hs(p) ready / end of phase
    }
    __syncthreads();  // matches consumer's final phase barrier (q=7 read)
  } else {
    // ================= CONSUMER (waves 4-7) =================
    const int wc = w - 4;  // out rows wc*64 .. +64
    f32x16 oacc[2][2];
#pragma unroll
    for (int i = 0; i < 2; ++i)
#pragma unroll
      for (int j = 0; j < 2; ++j)
#pragma unroll
        for (int r = 0; r < 16; ++r) oacc[i][j][r] = 0.f;

    // ---- shared expert: rf2 cf2, K=256; 4 groups of {burst 8 A, 16 MFMA} ----
    {
      const unsigned short* As = wshp + (size_t)(wc * 2) * 16 * 512 + l * 8;
#pragma unroll
      for (int g = 0; g < 4; ++g) {
        bf16x8 a0f[4], a1f[4];
#pragma unroll
        for (int j = 0; j < 4; ++j) {
          a0f[j] = *reinterpret_cast<const bf16x8*>(As + (g * 4 + j) * 512);
          a1f[j] = *reinterpret_cast<const bf16x8*>(As + 8192 + (g * 4 + j) * 512);
        }
        SBAR();
        __builtin_amdgcn_s_setprio(1);
#pragma unroll
        for (int j = 0; j < 4; ++j) {
          const bf16x8 b0 = *reinterpret_cast<const bf16x8*>(xB0 + (g * 4 + j) * 1024);
          const bf16x8 b1 = *reinterpret_cast<const bf16x8*>(xB1 + (g * 4 + j) * 1024);
          oacc[0][0] = MFMA32(a0f[j], b0, oacc[0][0]);
          oacc[0][1] = MFMA32(a0f[j], b1, oacc[0][1]);
          oacc[1][0] = MFMA32(a1f[j], b0, oacc[1][0]);
          oacc[1][1] = MFMA32(a1f[j], b1, oacc[1][1]);
        }
        __builtin_amdgcn_s_setprio(0);
      }
    }
#pragma unroll
    for (int i = 0; i < 2; ++i)
#pragma unroll
      for (int j = 0; j < 2; ++j)
#pragma unroll
        for (int r = 0; r < 16; ++r) oacc[i][j][r] = silu_f(oacc[i][j][r]);

    __syncthreads();  // hs(0) ready (producer's phase-0 barrier)
#pragma unroll 1
    for (int q = 0; q < 8; ++q) {
      const int e = (q >> 2) ? e1 : e0, ch = q & 3;
      const unsigned short* A2 =
          w2p + ((size_t)(e * 8 + wc * 2) * 32 + ch * 8) * 512 + l * 8;
      const unsigned short* hB0 = hs[q & 1] + (lh * 64 + l31) * 8;
      const unsigned short* hB1 = hB0 + 256;
      // 2 groups of {burst 8 A-frags (32 VGPR), 16 MFMAs}
#pragma unroll
      for (int g = 0; g < 2; ++g) {
        bf16x8 a0f[4], a1f[4];
#pragma unroll
        for (int j = 0; j < 4; ++j) {
          a0f[j] = *reinterpret_cast<const bf16x8*>(A2 + (g * 4 + j) * 512);
          a1f[j] = *reinterpret_cast<const bf16x8*>(A2 + 16384 + (g * 4 + j) * 512);
        }
        SBAR();
        __builtin_amdgcn_s_setprio(1);
#pragma unroll
        for (int j = 0; j < 4; ++j) {
          const bf16x8 h0 = *reinterpret_cast<const bf16x8*>(hB0 + (g * 4 + j) * 1024);
          const bf16x8 h1 = *reinterpret_cast<const bf16x8*>(hB1 + (g * 4 + j) * 1024);
          oacc[0][0] = MFMA32(a0f[j], h0, oacc[0][0]);
          oacc[0][1] = MFMA32(a0f[j], h1, oacc[0][1]);
          oacc[1][0] = MFMA32(a1f[j], h0, oacc[1][0]);
          oacc[1][1] = MFMA32(a1f[j], h1, oacc[1][1]);
        }
        __builtin_amdgcn_s_setprio(0);
      }
      __syncthreads();  // end of phase q
    }

    // ---- write out[b, o, px] ----
#pragma unroll
    for (int rfi = 0; rfi < 2; ++rfi)
#pragma unroll
      for (int cf = 0; cf < 2; ++cf)
#pragma unroll
        for (int r = 0; r < 16; ++r) {
          const int o = wc * 64 + rfi * 32 + (r & 3) + 8 * (r >> 2) + 4 * lh;
          out[((size_t)b * 256 + o) * HW + px0 + cf * 32 + l31] = oacc[rfi][cf][r];
        }
  }
}

extern "C" void kernel_launch(void* const* d_in, const int* in_sizes, int n_in,
                              void* d_out, int out_size, void* d_ws, size_t ws_size,
                              hipStream_t stream) {
  const float* x = (const float*)d_in[0];
  const float* rw1 = (const float*)d_in[1];
  const float* rw2 = (const float*)d_in[2];
  const float* ew1 = (const float*)d_in[3];
  const float* ew2 = (const float*)d_in[4];
  const float* shw = (const float*)d_in[5];
  float* out = (float*)d_out;
  char* ws = (char*)d_ws;

  float* xp = (float*)(ws);                                // 3,211,264 B
  float* hsum = (float*)(ws + 3211264);
  float* selv = (float*)(ws + 3213312);
  int* sele = (int*)(ws + 3213440);
  unsigned short* wshp = (unsigned short*)(ws + 3213568);  // 128 KB
  unsigned short* w1p = wshp + 65536;                      // 1 MB
  unsigned short* w2p = w1p + 524288;                      // 1 MB

  prep_k<<<7488, 256, 0, stream>>>(shw, ew1, ew2, x, wshp, w1p, w2p, xp);
  router_conv_k<<<512, 256, 0, stream>>>(xp, rw1, hsum);
  topk_k<<<1, 64, 0, stream>>>(hsum, rw2, selv, sele);
  moe_main_k<<<784, 512, 0, stream>>>(x, wshp, w1p, w2p, selv, sele, out);
}